// Round 13
// baseline (278.566 us; speedup 1.0000x reference)
//
#include <hip/hip_runtime.h>
#include <cstdint>
#include <cstddef>

#define N_NODES   100000
#define N_EDGES   1600000
#define D_IN      128
#define HIDDEN    64
#define N_GRAPHS  512
#define N_CLASSES 10

#define NB   196          // buckets (dst>>9), 512 nodes each; 99999>>9 = 195
#define EB   1563         // hist edge-blocks, 1024 edges each
#define EB4  391          // scatter blocks, 4096 edges each (4 hist-blocks)
#define NBE  (NB * EB)    // 306,348 count-matrix entries
#define BCAP 12288        // per-bucket LDS srcs capacity (avg 8163, std ~90)
#define PSLOTS 8          // graphs spanned per 32-node gather block (avg ~1.2)

typedef __attribute__((ext_vector_type(8))) short bf16x8;
typedef __attribute__((ext_vector_type(4))) float f32x4;
typedef __attribute__((ext_vector_type(2))) float f32x2;

// ---- bf16 helpers ----
__device__ inline float bf2f(unsigned short u) {
    return __uint_as_float(((unsigned int)u) << 16);
}
__device__ inline unsigned short f2bf(float f) {
    unsigned int x = __float_as_uint(f);
    return (unsigned short)((x + 0x7FFF + ((x >> 16) & 1)) >> 16);
}

// ===========================================================================
// Generic exclusive scan, 4096 ints per 256-thread block (3 kernels).
// ===========================================================================
__global__ __launch_bounds__(256)
void scan1_kernel(const int* __restrict__ in, int* __restrict__ bsum, int n) {
    __shared__ int lds[256];
    int tid = threadIdx.x;
    int base = blockIdx.x * 4096 + tid * 16;
    int s = 0;
#pragma unroll
    for (int j = 0; j < 16; j++) { int i = base + j; if (i < n) s += in[i]; }
    lds[tid] = s; __syncthreads();
    for (int off = 128; off > 0; off >>= 1) {
        if (tid < off) lds[tid] += lds[tid + off];
        __syncthreads();
    }
    if (tid == 0) bsum[blockIdx.x] = lds[0];
}

__global__ __launch_bounds__(256)
void scan2_kernel(int* __restrict__ bsum, int* __restrict__ out, int nb, int n) {
    __shared__ int lds[256];
    int tid = threadIdx.x;
    int v = (tid < nb) ? bsum[tid] : 0;
    lds[tid] = v; __syncthreads();
    for (int off = 1; off < 256; off <<= 1) {
        int t = (tid >= off) ? lds[tid - off] : 0;
        __syncthreads();
        lds[tid] += t;
        __syncthreads();
    }
    if (tid < nb) bsum[tid] = lds[tid] - v;   // exclusive block offsets
    if (tid == 255) out[n] = lds[255];        // grand total (= N_EDGES)
}

__global__ __launch_bounds__(256)
void scan3_kernel(const int* __restrict__ in, const int* __restrict__ bsum,
                  int* __restrict__ out, int n) {
    __shared__ int lds[256];
    int tid = threadIdx.x;
    int base = blockIdx.x * 4096 + tid * 16;
    int v[16]; int s = 0;
#pragma unroll
    for (int j = 0; j < 16; j++) {
        int i = base + j;
        v[j] = (i < n) ? in[i] : 0;
        s += v[j];
    }
    lds[tid] = s; __syncthreads();
    for (int off = 1; off < 256; off <<= 1) {
        int t = (tid >= off) ? lds[tid - off] : 0;
        __syncthreads();
        lds[tid] += t;
        __syncthreads();
    }
    int ex = lds[tid] - s + bsum[blockIdx.x];
#pragma unroll
    for (int j = 0; j < 16; j++) {
        int i = base + j;
        if (i < n) { out[i] = ex; ex += v[j]; }
    }
}

// ===========================================================================
// Fused 1: even blocks = gemm1 (x fp32 @ W1 -> bf16), odd = bucket histogram
// via LDS atomics (NO global atomics). HA layout: [bucket][edge_block].
// ===========================================================================
__global__ __launch_bounds__(256)
void fused1_kernel(const float* __restrict__ X, const float* __restrict__ W,
                   unsigned short* __restrict__ H,
                   const int* __restrict__ dst, int* __restrict__ HA) {
    const int tid = threadIdx.x;
    if (blockIdx.x & 1) {
        __shared__ int cnt[NB];
        int hb = blockIdx.x >> 1;
        for (int i = tid; i < NB; i += 256) cnt[i] = 0;
        __syncthreads();
        int base = hb * 1024 + tid;
#pragma unroll
        for (int j = 0; j < 4; j++) {
            int t = base + j * 256;
            if (t < N_EDGES) atomicAdd(&cnt[dst[t] >> 9], 1);
        }
        __syncthreads();
        for (int b = tid; b < NB; b += 256) HA[b * EB + hb] = cnt[b];
        return;
    }

    constexpr int K  = D_IN;
    constexpr int KP = K + 8;
    __shared__ unsigned short As[64 * KP];
    __shared__ unsigned short Wt[64 * KP];

    const int row0 = (blockIdx.x >> 1) * 64;

    for (int i = tid; i < K * 64; i += 256) {
        int k = i >> 6;
        int n = i & 63;
        Wt[n * KP + k] = f2bf(W[i]);
    }
    constexpr int KQ = K / 4;
    for (int i = tid; i < 64 * KQ; i += 256) {
        int r = i / KQ, k4 = i % KQ;
        int row = row0 + r;
        float4 v = make_float4(0.f, 0.f, 0.f, 0.f);
        if (row < N_NODES) v = ((const float4*)(X + (size_t)row * K))[k4];
        ushort4 o = make_ushort4(f2bf(v.x), f2bf(v.y), f2bf(v.z), f2bf(v.w));
        *(ushort4*)&As[r * KP + k4 * 4] = o;
    }
    __syncthreads();

    const int wave = tid >> 6;
    const int lane = tid & 63;
    const int lrow = lane & 15;
    const int quad = lane >> 4;
    const int m = wave * 16 + lrow;

    f32x4 acc0 = {0.f, 0.f, 0.f, 0.f};
    f32x4 acc1 = {0.f, 0.f, 0.f, 0.f};
    f32x4 acc2 = {0.f, 0.f, 0.f, 0.f};
    f32x4 acc3 = {0.f, 0.f, 0.f, 0.f};

#pragma unroll
    for (int kt = 0; kt < K / 32; kt++) {
        int k0 = kt * 32 + quad * 8;
        bf16x8 a = *(const bf16x8*)&As[m * KP + k0];
        bf16x8 b0 = *(const bf16x8*)&Wt[(0 * 16 + lrow) * KP + k0];
        bf16x8 b1 = *(const bf16x8*)&Wt[(1 * 16 + lrow) * KP + k0];
        bf16x8 b2 = *(const bf16x8*)&Wt[(2 * 16 + lrow) * KP + k0];
        bf16x8 b3 = *(const bf16x8*)&Wt[(3 * 16 + lrow) * KP + k0];
        acc0 = __builtin_amdgcn_mfma_f32_16x16x32_bf16(a, b0, acc0, 0, 0, 0);
        acc1 = __builtin_amdgcn_mfma_f32_16x16x32_bf16(a, b1, acc1, 0, 0, 0);
        acc2 = __builtin_amdgcn_mfma_f32_16x16x32_bf16(a, b2, acc2, 0, 0, 0);
        acc3 = __builtin_amdgcn_mfma_f32_16x16x32_bf16(a, b3, acc3, 0, 0, 0);
    }

    f32x4 accs[4] = {acc0, acc1, acc2, acc3};
#pragma unroll
    for (int c = 0; c < 4; c++) {
#pragma unroll
        for (int r = 0; r < 4; r++) {
            int row = row0 + wave * 16 + quad * 4 + r;
            if (row < N_NODES) H[(size_t)row * 64 + c * 16 + lrow] = f2bf(accs[c][r]);
        }
    }
}

// ===========================================================================
// scatterA2: bucket-sort edges, 4096 edges/block, packed int2 {dst,src}.
// ===========================================================================
__global__ __launch_bounds__(256)
void scatterA2_kernel(const int* __restrict__ src, const int* __restrict__ dst,
                      const int* __restrict__ posA, int2* __restrict__ edgeA) {
    __shared__ int off[NB];
    int tid = threadIdx.x, blk = blockIdx.x;
    for (int b = tid; b < NB; b += 256) off[b] = posA[b * EB + blk * 4];
    __syncthreads();
    int base = blk * 4096 + tid;
#pragma unroll
    for (int j = 0; j < 16; j++) {
        int t = base + j * 256;
        if (t < N_EDGES) {
            int d = dst[t];
            int r = atomicAdd(&off[d >> 9], 1);
            edgeA[r] = make_int2(d, src[t]);
        }
    }
}

// ===========================================================================
// passB: one block per bucket. Local hist -> dinv, local scan -> noffs,
// LDS scatter -> node-major srcs2.
// ===========================================================================
__global__ __launch_bounds__(256)
void passB_kernel(const int* __restrict__ posA, const int2* __restrict__ edgeA,
                  int* __restrict__ noffs, float* __restrict__ dinv,
                  int* __restrict__ srcs2) {
    __shared__ int hist[512];
    __shared__ int off[512];
    __shared__ int ps[256];
    __shared__ int srcs_l[BCAP];

    int tid = threadIdx.x, b = blockIdx.x;
    int e0 = posA[b * EB];
    int e1 = posA[(b + 1) * EB];
    int n0 = b << 9;
    int nn = min(512, N_NODES - n0);
    int len = e1 - e0;

    hist[tid] = 0; hist[tid + 256] = 0;
    __syncthreads();
    for (int i = e0 + tid; i < e1; i += 256) atomicAdd(&hist[edgeA[i].x - n0], 1);
    __syncthreads();

    for (int n = tid; n < nn; n += 256) dinv[n0 + n] = rsqrtf((float)hist[n] + 1.0f);

    int a0 = hist[2 * tid], a1 = hist[2 * tid + 1];
    ps[tid] = a0 + a1;
    __syncthreads();
    for (int d = 1; d < 256; d <<= 1) {
        int v = (tid >= d) ? ps[tid - d] : 0;
        __syncthreads();
        ps[tid] += v;
        __syncthreads();
    }
    int pre = ps[tid] - (a0 + a1);
    off[2 * tid] = pre;
    off[2 * tid + 1] = pre + a0;
    __syncthreads();

    for (int n = tid; n < nn; n += 256) noffs[n0 + n] = e0 + off[n];
    if (b == NB - 1 && tid == 0) noffs[N_NODES] = N_EDGES;
    __syncthreads();

    if (len <= BCAP) {
        for (int i = e0 + tid; i < e1; i += 256) {
            int2 e = edgeA[i];
            int r = atomicAdd(&off[e.x - n0], 1);
            srcs_l[r] = e.y;
        }
        __syncthreads();
        for (int i = tid; i < len; i += 256) srcs2[e0 + i] = srcs_l[i];
    } else {
        for (int i = e0 + tid; i < e1; i += 256) {
            int2 e = edgeA[i];
            int r = atomicAdd(&off[e.x - n0], 1);
            srcs2[e0 + r] = e.y;
        }
    }
}

// ===========================================================================
// MFMA GEMM (layer 2): bf16 in, fp8-e4m3 out (HW cvt), K=64.
// ===========================================================================
template <int K>
__global__ __launch_bounds__(256)
void gemm_mfma_fp8out_kernel(const unsigned short* __restrict__ X, const float* __restrict__ W,
                             unsigned char* __restrict__ H8, int n_rows) {
    constexpr int KP = K + 8;
    __shared__ unsigned short As[64 * KP];
    __shared__ unsigned short Wt[64 * KP];

    const int tid  = threadIdx.x;
    const int row0 = blockIdx.x * 64;

    for (int i = tid; i < K * 64; i += 256) {
        int k = i >> 6;
        int n = i & 63;
        Wt[n * KP + k] = f2bf(W[i]);
    }
    constexpr int KQ = K / 8;
    for (int i = tid; i < 64 * KQ; i += 256) {
        int r = i / KQ, k8 = i % KQ;
        int row = row0 + r;
        int4 v = make_int4(0, 0, 0, 0);
        if (row < n_rows) v = ((const int4*)(X + (size_t)row * K))[k8];
        *(int4*)&As[r * KP + k8 * 8] = v;
    }
    __syncthreads();

    const int wave = tid >> 6;
    const int lane = tid & 63;
    const int lrow = lane & 15;
    const int quad = lane >> 4;
    const int m = wave * 16 + lrow;

    f32x4 acc0 = {0.f, 0.f, 0.f, 0.f};
    f32x4 acc1 = {0.f, 0.f, 0.f, 0.f};
    f32x4 acc2 = {0.f, 0.f, 0.f, 0.f};
    f32x4 acc3 = {0.f, 0.f, 0.f, 0.f};

#pragma unroll
    for (int kt = 0; kt < K / 32; kt++) {
        int k0 = kt * 32 + quad * 8;
        bf16x8 a = *(const bf16x8*)&As[m * KP + k0];
        bf16x8 b0 = *(const bf16x8*)&Wt[(0 * 16 + lrow) * KP + k0];
        bf16x8 b1 = *(const bf16x8*)&Wt[(1 * 16 + lrow) * KP + k0];
        bf16x8 b2 = *(const bf16x8*)&Wt[(2 * 16 + lrow) * KP + k0];
        bf16x8 b3 = *(const bf16x8*)&Wt[(3 * 16 + lrow) * KP + k0];
        acc0 = __builtin_amdgcn_mfma_f32_16x16x32_bf16(a, b0, acc0, 0, 0, 0);
        acc1 = __builtin_amdgcn_mfma_f32_16x16x32_bf16(a, b1, acc1, 0, 0, 0);
        acc2 = __builtin_amdgcn_mfma_f32_16x16x32_bf16(a, b2, acc2, 0, 0, 0);
        acc3 = __builtin_amdgcn_mfma_f32_16x16x32_bf16(a, b3, acc3, 0, 0, 0);
    }

    f32x4 accs[4] = {acc0, acc1, acc2, acc3};
#pragma unroll
    for (int c = 0; c < 4; c++) {
#pragma unroll
        for (int r = 0; r < 4; r++) {
            int row = row0 + wave * 16 + quad * 4 + r;
            if (row < n_rows) {
                int p = __builtin_amdgcn_cvt_pk_fp8_f32(accs[c][r], accs[c][r], 0, false);
                H8[(size_t)row * 64 + c * 16 + lrow] = (unsigned char)(p & 0xFF);
            }
        }
    }
}

// ===========================================================================
// Gather A (layer 1): bf16 table, 8 lanes/node, x4 unroll -> bf16 out.
// ===========================================================================
__device__ inline void upk_fma(int4 u, float c, float* acc) {
    unsigned int a = (unsigned int)u.x, b = (unsigned int)u.y;
    unsigned int d = (unsigned int)u.z, e = (unsigned int)u.w;
    acc[0] += __uint_as_float(a << 16) * c;
    acc[1] += __uint_as_float(a & 0xFFFF0000u) * c;
    acc[2] += __uint_as_float(b << 16) * c;
    acc[3] += __uint_as_float(b & 0xFFFF0000u) * c;
    acc[4] += __uint_as_float(d << 16) * c;
    acc[5] += __uint_as_float(d & 0xFFFF0000u) * c;
    acc[6] += __uint_as_float(e << 16) * c;
    acc[7] += __uint_as_float(e & 0xFFFF0000u) * c;
}

__global__ __launch_bounds__(256)
void gather_flat_kernel(const int* __restrict__ offs, const int* __restrict__ srcs,
                        const float* __restrict__ dinv, const unsigned short* __restrict__ h,
                        const float* __restrict__ b, unsigned short* __restrict__ out,
                        int n_nodes) {
    int t = blockIdx.x * 256 + threadIdx.x;
    int node = t >> 3;
    if (node >= n_nodes) return;
    int cg = (t & 7) * 8;

    float dn = dinv[node];
    float acc[8];
    {
        int4 u = *(const int4*)(h + (size_t)node * 64 + cg);
        float c2 = dn * dn;
        for (int j = 0; j < 8; j++) acc[j] = 0.f;
        upk_fma(u, c2, acc);
    }

    int i  = offs[node];
    int i1 = offs[node + 1];
    for (; i + 4 <= i1; i += 4) {
        int s0 = srcs[i];
        int s1 = srcs[i + 1];
        int s2 = srcs[i + 2];
        int s3 = srcs[i + 3];
        float c0 = dinv[s0] * dn;
        float c1 = dinv[s1] * dn;
        float c2 = dinv[s2] * dn;
        float c3 = dinv[s3] * dn;
        int4 u0 = *(const int4*)(h + (size_t)s0 * 64 + cg);
        int4 u1 = *(const int4*)(h + (size_t)s1 * 64 + cg);
        int4 u2 = *(const int4*)(h + (size_t)s2 * 64 + cg);
        int4 u3 = *(const int4*)(h + (size_t)s3 * 64 + cg);
        upk_fma(u0, c0, acc);
        upk_fma(u1, c1, acc);
        upk_fma(u2, c2, acc);
        upk_fma(u3, c3, acc);
    }
    for (; i < i1; i++) {
        int s0 = srcs[i];
        float c0 = dinv[s0] * dn;
        int4 u0 = *(const int4*)(h + (size_t)s0 * 64 + cg);
        upk_fma(u0, c0, acc);
    }

    float4 b0 = *(const float4*)(b + cg);
    float4 b1 = *(const float4*)(b + cg + 4);
    unsigned short* o = out + (size_t)node * 64 + cg;
    ushort4 p0 = make_ushort4(f2bf(fmaxf(acc[0] + b0.x, 0.f)), f2bf(fmaxf(acc[1] + b0.y, 0.f)),
                              f2bf(fmaxf(acc[2] + b0.z, 0.f)), f2bf(fmaxf(acc[3] + b0.w, 0.f)));
    ushort4 p1 = make_ushort4(f2bf(fmaxf(acc[4] + b1.x, 0.f)), f2bf(fmaxf(acc[5] + b1.y, 0.f)),
                              f2bf(fmaxf(acc[6] + b1.z, 0.f)), f2bf(fmaxf(acc[7] + b1.w, 0.f)));
    *(ushort4*)(o)     = p0;
    *(ushort4*)(o + 4) = p1;
}

// ===========================================================================
// Gather B + POOL fused (layer 2): fp8 table, 8 lanes/node; after bias+relu
// the node's r[8] goes straight into an LDS pool (batch sorted -> a 32-node
// block spans ~1-2 graphs), flushed once per block with non-returning
// global atomics. Kills the pool dispatch and the 25.6 MB out2 round-trip.
// ===========================================================================
__device__ inline void upk8_fma(int2 u, float c, float* acc) {
    f32x2 p0 = __builtin_amdgcn_cvt_pk_f32_fp8(u.x, false);
    f32x2 p1 = __builtin_amdgcn_cvt_pk_f32_fp8(u.x, true);
    f32x2 p2 = __builtin_amdgcn_cvt_pk_f32_fp8(u.y, false);
    f32x2 p3 = __builtin_amdgcn_cvt_pk_f32_fp8(u.y, true);
    acc[0] += p0.x * c; acc[1] += p0.y * c;
    acc[2] += p1.x * c; acc[3] += p1.y * c;
    acc[4] += p2.x * c; acc[5] += p2.y * c;
    acc[6] += p3.x * c; acc[7] += p3.y * c;
}

__global__ __launch_bounds__(256)
void gather_fp8_pool_kernel(const int* __restrict__ offs, const int* __restrict__ srcs,
                            const float* __restrict__ dinv, const unsigned char* __restrict__ h8,
                            const float* __restrict__ b, const int* __restrict__ batch,
                            float* __restrict__ pooled, float* __restrict__ cnt,
                            int n_nodes) {
    __shared__ float pacc[PSLOTS][64];
    __shared__ float lcnt[PSLOTS];
    __shared__ int sg0;

    int tid = threadIdx.x;
    int node0 = blockIdx.x * 32;
    for (int i = tid; i < PSLOTS * 64; i += 256) ((float*)pacc)[i] = 0.f;
    if (tid < PSLOTS) lcnt[tid] = 0.f;
    if (tid == 0) sg0 = batch[node0 < n_nodes ? node0 : (n_nodes - 1)];
    __syncthreads();
    int g0 = sg0;

    int node = node0 + (tid >> 3);
    int cg = (tid & 7) * 8;

    if (node < n_nodes) {
        float dn = dinv[node];
        float acc[8];
        {
            int2 u = *(const int2*)(h8 + (size_t)node * 64 + cg);
            float c2 = dn * dn;
            for (int j = 0; j < 8; j++) acc[j] = 0.f;
            upk8_fma(u, c2, acc);
        }

        int i  = offs[node];
        int i1 = offs[node + 1];
        for (; i + 4 <= i1; i += 4) {
            int s0 = srcs[i];
            int s1 = srcs[i + 1];
            int s2 = srcs[i + 2];
            int s3 = srcs[i + 3];
            float c0 = dinv[s0] * dn;
            float c1 = dinv[s1] * dn;
            float c2 = dinv[s2] * dn;
            float c3 = dinv[s3] * dn;
            int2 u0 = *(const int2*)(h8 + (size_t)s0 * 64 + cg);
            int2 u1 = *(const int2*)(h8 + (size_t)s1 * 64 + cg);
            int2 u2 = *(const int2*)(h8 + (size_t)s2 * 64 + cg);
            int2 u3 = *(const int2*)(h8 + (size_t)s3 * 64 + cg);
            upk8_fma(u0, c0, acc);
            upk8_fma(u1, c1, acc);
            upk8_fma(u2, c2, acc);
            upk8_fma(u3, c3, acc);
        }
        for (; i < i1; i++) {
            int s0 = srcs[i];
            float c0 = dinv[s0] * dn;
            int2 u0 = *(const int2*)(h8 + (size_t)s0 * 64 + cg);
            upk8_fma(u0, c0, acc);
        }

        float4 b0 = *(const float4*)(b + cg);
        float4 b1 = *(const float4*)(b + cg + 4);
        float r[8];
        r[0] = fmaxf(acc[0] + b0.x, 0.f);
        r[1] = fmaxf(acc[1] + b0.y, 0.f);
        r[2] = fmaxf(acc[2] + b0.z, 0.f);
        r[3] = fmaxf(acc[3] + b0.w, 0.f);
        r[4] = fmaxf(acc[4] + b1.x, 0.f);
        r[5] = fmaxf(acc[5] + b1.y, 0.f);
        r[6] = fmaxf(acc[6] + b1.z, 0.f);
        r[7] = fmaxf(acc[7] + b1.w, 0.f);

        int g = batch[node];
        int slot = g - g0;          // batch sorted -> slot >= 0
        if (slot < PSLOTS) {
#pragma unroll
            for (int j = 0; j < 8; j++) atomicAdd(&pacc[slot][cg + j], r[j]);
            if ((tid & 7) == 0) atomicAdd(&lcnt[slot], 1.f);
        } else {
            // rare: block spans >PSLOTS graphs
#pragma unroll
            for (int j = 0; j < 8; j++) unsafeAtomicAdd(&pooled[(size_t)g * 64 + cg + j], r[j]);
            if ((tid & 7) == 0) unsafeAtomicAdd(&cnt[g], 1.f);
        }
    }
    __syncthreads();

    // flush (non-returning atomics; zero-valued slots are no-ops and skipped)
    for (int i = tid; i < PSLOTS * 64; i += 256) {
        float v = ((float*)pacc)[i];
        if (v != 0.f) unsafeAtomicAdd(&pooled[(size_t)(g0 + (i >> 6)) * 64 + (i & 63)], v);
    }
    if (tid < PSLOTS && lcnt[tid] != 0.f) unsafeAtomicAdd(&cnt[g0 + tid], lcnt[tid]);
}

// ===========================================================================
// Head: pooled mean -> logits -> log_softmax.
// ===========================================================================
__global__ __launch_bounds__(256)
void head_kernel(const float* __restrict__ pooled, const float* __restrict__ cnt,
                 const float* __restrict__ Wfc, const float* __restrict__ bfc,
                 float* __restrict__ out) {
    __shared__ float Ws[HIDDEN * N_CLASSES];
    __shared__ float bs[N_CLASSES];
    int tid = threadIdx.x;
    for (int i = tid; i < HIDDEN * N_CLASSES; i += 256) Ws[i] = Wfc[i];
    if (tid < N_CLASSES) bs[tid] = bfc[tid];
    __syncthreads();

    int g = blockIdx.x * 256 + tid;
    if (g >= N_GRAPHS) return;

    float inv = 1.f / fmaxf(cnt[g], 1.f);
    float p[HIDDEN];
#pragma unroll
    for (int k = 0; k < HIDDEN; k++) p[k] = pooled[(size_t)g * 64 + k] * inv;

    float lg[N_CLASSES];
    float m = -1e30f;
#pragma unroll
    for (int j = 0; j < N_CLASSES; j++) {
        float a = bs[j];
#pragma unroll
        for (int k = 0; k < HIDDEN; k++) a += p[k] * Ws[k * N_CLASSES + j];
        lg[j] = a;
        m = fmaxf(m, a);
    }
    float s = 0.f;
#pragma unroll
    for (int j = 0; j < N_CLASSES; j++) s += __expf(lg[j] - m);
    float lse = m + __logf(s);
#pragma unroll
    for (int j = 0; j < N_CLASSES; j++) out[(size_t)g * N_CLASSES + j] = lg[j] - lse;
}

// ===========================================================================
// Launch
// ===========================================================================
extern "C" void kernel_launch(void* const* d_in, const int* in_sizes, int n_in,
                              void* d_out, int out_size, void* d_ws, size_t ws_size,
                              hipStream_t stream) {
    const float* x   = (const float*)d_in[0];
    const int*   ei  = (const int*)d_in[1];
    const int*   bat = (const int*)d_in[2];
    const float* W1  = (const float*)d_in[3];
    const float* b1  = (const float*)d_in[4];
    const float* W2  = (const float*)d_in[5];
    const float* b2  = (const float*)d_in[6];
    const float* Wfc = (const float*)d_in[7];
    const float* bfc = (const float*)d_in[8];
    float* out = (float*)d_out;

    const int* src = ei;
    const int* dst = ei + N_EDGES;

    char* ws = (char*)d_ws;

    // Layout, total ~53.8 MB:
    const size_t OFF_H     = 0;          // h1 bf16 12.8 MB; later h2 fp8 6.4 MB
    const size_t OFF_SRCS2 = 12800000;   // node-major srcs 6.4 MB
    const size_t OFF_NOFFS = 19200000;   // 400,016
    const size_t OFF_DINV  = 19600016;   // 400,000
    const size_t OFF_BUFB  = 25600000;   // h1r bf16 12.8 MB
    const size_t OFF_EDGEA = 38400000;   // 12.8 MB int2 {dst,src} (build only)
    const size_t OFF_HA    = 51200000;   // 1,225,392
    const size_t OFF_POSA  = 52425392;   // 1,225,396 (NBE+1 ints)
    const size_t OFF_BSUM  = 53650800;   // 1,024
    const size_t OFF_POOL  = 53651824;   // 131,072
    const size_t OFF_CNT   = 53782896;   // 2,048

    unsigned short* hbuf  = (unsigned short*)(ws + OFF_H);
    unsigned char*  hbuf8 = (unsigned char*) (ws + OFF_H);
    int*   srcs2  = (int*)  (ws + OFF_SRCS2);
    int*   noffs  = (int*)  (ws + OFF_NOFFS);
    float* dinv   = (float*)(ws + OFF_DINV);
    unsigned short* bufB16 = (unsigned short*)(ws + OFF_BUFB);
    int2*  edgeA  = (int2*) (ws + OFF_EDGEA);
    int*   HA     = (int*)  (ws + OFF_HA);
    int*   posA   = (int*)  (ws + OFF_POSA);
    int*   bsum   = (int*)  (ws + OFF_BSUM);
    float* pooled = (float*)(ws + OFF_POOL);
    float* cnt    = (float*)(ws + OFF_CNT);

    const int SCAN_BLOCKS = (NBE + 4095) / 4096;          // 75
    const int GATHER_BLOCKS = (N_NODES * 8 + 255) / 256;  // 3125
    const int GEMM_BLOCKS = (N_NODES + 63) / 64;          // 1563

    hipMemsetAsync(pooled, 0, (size_t)(N_GRAPHS * 64 + N_GRAPHS) * sizeof(float), stream);

    // 1. gemm1 (even blocks) + bucket histogram via LDS (odd blocks)
    fused1_kernel<<<2 * GEMM_BLOCKS, 256, 0, stream>>>(x, W1, hbuf, dst, HA);
    // 2. scan the (bucket, block) count matrix -> exclusive slots
    scan1_kernel<<<SCAN_BLOCKS, 256, 0, stream>>>(HA, bsum, NBE);
    scan2_kernel<<<1, 256, 0, stream>>>(bsum, posA, SCAN_BLOCKS, NBE);
    scan3_kernel<<<SCAN_BLOCKS, 256, 0, stream>>>(HA, bsum, posA, NBE);
    // 3. bucket-sort edges: 4096-edge blocks, packed int2, no global atomics
    scatterA2_kernel<<<EB4, 256, 0, stream>>>(src, dst, posA, edgeA);
    // 4. per-bucket CSR build: degrees->dinv, noffs, node-major srcs2
    passB_kernel<<<NB, 256, 0, stream>>>(posA, edgeA, noffs, dinv, srcs2);

    // 5. gather1 (bf16 table): h1 -> h1r bf16
    gather_flat_kernel<<<GATHER_BLOCKS, 256, 0, stream>>>(noffs, srcs2, dinv, hbuf, b1, bufB16, N_NODES);
    // 6. gemm2: h1r bf16 -> h2 fp8
    gemm_mfma_fp8out_kernel<HIDDEN><<<GEMM_BLOCKS, 256, 0, stream>>>(bufB16, W2, hbuf8, N_NODES);
    // 7. gather2 + pool fused: h2 fp8 -> pooled/cnt directly (no out2 buffer)
    gather_fp8_pool_kernel<<<GATHER_BLOCKS, 256, 0, stream>>>(
        noffs, srcs2, dinv, hbuf8, b2, bat, pooled, cnt, N_NODES);

    // 8. head
    head_kernel<<<(N_GRAPHS + 255) / 256, 256, 0, stream>>>(pooled, cnt, Wfc, bfc, out);
}

// Round 14
// 265.561 us; speedup vs baseline: 1.0490x; 1.0490x over previous
//
#include <hip/hip_runtime.h>
#include <cstdint>
#include <cstddef>

#define N_NODES   100000
#define N_EDGES   1600000
#define D_IN      128
#define HIDDEN    64
#define N_GRAPHS  512
#define N_CLASSES 10

#define NB   196          // buckets (dst>>9), 512 nodes each; 99999>>9 = 195
#define EB   1563         // hist edge-blocks, 1024 edges each
#define EB4  391          // scatter blocks, 4096 edges each (4 hist-blocks)
#define NBE  (NB * EB)    // 306,348 count-matrix entries
#define BCAP 12288        // per-bucket LDS srcs capacity (avg 8163, std ~90)
#define PSLOTS 8          // graphs spanned per 32-node gather block (avg ~1.2)

typedef __attribute__((ext_vector_type(8))) short bf16x8;
typedef __attribute__((ext_vector_type(4))) float f32x4;
typedef __attribute__((ext_vector_type(2))) float f32x2;

// ---- bf16 helpers ----
__device__ inline float bf2f(unsigned short u) {
    return __uint_as_float(((unsigned int)u) << 16);
}
__device__ inline unsigned short f2bf(float f) {
    unsigned int x = __float_as_uint(f);
    return (unsigned short)((x + 0x7FFF + ((x >> 16) & 1)) >> 16);
}

// ===========================================================================
// Generic exclusive scan, 4096 ints per 256-thread block (3 kernels).
// ===========================================================================
__global__ __launch_bounds__(256)
void scan1_kernel(const int* __restrict__ in, int* __restrict__ bsum, int n) {
    __shared__ int lds[256];
    int tid = threadIdx.x;
    int base = blockIdx.x * 4096 + tid * 16;
    int s = 0;
#pragma unroll
    for (int j = 0; j < 16; j++) { int i = base + j; if (i < n) s += in[i]; }
    lds[tid] = s; __syncthreads();
    for (int off = 128; off > 0; off >>= 1) {
        if (tid < off) lds[tid] += lds[tid + off];
        __syncthreads();
    }
    if (tid == 0) bsum[blockIdx.x] = lds[0];
}

__global__ __launch_bounds__(256)
void scan2_kernel(int* __restrict__ bsum, int* __restrict__ out, int nb, int n) {
    __shared__ int lds[256];
    int tid = threadIdx.x;
    int v = (tid < nb) ? bsum[tid] : 0;
    lds[tid] = v; __syncthreads();
    for (int off = 1; off < 256; off <<= 1) {
        int t = (tid >= off) ? lds[tid - off] : 0;
        __syncthreads();
        lds[tid] += t;
        __syncthreads();
    }
    if (tid < nb) bsum[tid] = lds[tid] - v;   // exclusive block offsets
    if (tid == 255) out[n] = lds[255];        // grand total (= N_EDGES)
}

__global__ __launch_bounds__(256)
void scan3_kernel(const int* __restrict__ in, const int* __restrict__ bsum,
                  int* __restrict__ out, int n) {
    __shared__ int lds[256];
    int tid = threadIdx.x;
    int base = blockIdx.x * 4096 + tid * 16;
    int v[16]; int s = 0;
#pragma unroll
    for (int j = 0; j < 16; j++) {
        int i = base + j;
        v[j] = (i < n) ? in[i] : 0;
        s += v[j];
    }
    lds[tid] = s; __syncthreads();
    for (int off = 1; off < 256; off <<= 1) {
        int t = (tid >= off) ? lds[tid - off] : 0;
        __syncthreads();
        lds[tid] += t;
        __syncthreads();
    }
    int ex = lds[tid] - s + bsum[blockIdx.x];
#pragma unroll
    for (int j = 0; j < 16; j++) {
        int i = base + j;
        if (i < n) { out[i] = ex; ex += v[j]; }
    }
}

// ===========================================================================
// Fused 1: even blocks = gemm1 (x fp32 @ W1 -> bf16), odd = bucket histogram
// via LDS atomics (NO global atomics). HA layout: [bucket][edge_block].
// ===========================================================================
__global__ __launch_bounds__(256)
void fused1_kernel(const float* __restrict__ X, const float* __restrict__ W,
                   unsigned short* __restrict__ H,
                   const int* __restrict__ dst, int* __restrict__ HA) {
    const int tid = threadIdx.x;
    if (blockIdx.x & 1) {
        __shared__ int cnt[NB];
        int hb = blockIdx.x >> 1;
        for (int i = tid; i < NB; i += 256) cnt[i] = 0;
        __syncthreads();
        int base = hb * 1024 + tid;
#pragma unroll
        for (int j = 0; j < 4; j++) {
            int t = base + j * 256;
            if (t < N_EDGES) atomicAdd(&cnt[dst[t] >> 9], 1);
        }
        __syncthreads();
        for (int b = tid; b < NB; b += 256) HA[b * EB + hb] = cnt[b];
        return;
    }

    constexpr int K  = D_IN;
    constexpr int KP = K + 8;
    __shared__ unsigned short As[64 * KP];
    __shared__ unsigned short Wt[64 * KP];

    const int row0 = (blockIdx.x >> 1) * 64;

    for (int i = tid; i < K * 64; i += 256) {
        int k = i >> 6;
        int n = i & 63;
        Wt[n * KP + k] = f2bf(W[i]);
    }
    constexpr int KQ = K / 4;
    for (int i = tid; i < 64 * KQ; i += 256) {
        int r = i / KQ, k4 = i % KQ;
        int row = row0 + r;
        float4 v = make_float4(0.f, 0.f, 0.f, 0.f);
        if (row < N_NODES) v = ((const float4*)(X + (size_t)row * K))[k4];
        ushort4 o = make_ushort4(f2bf(v.x), f2bf(v.y), f2bf(v.z), f2bf(v.w));
        *(ushort4*)&As[r * KP + k4 * 4] = o;
    }
    __syncthreads();

    const int wave = tid >> 6;
    const int lane = tid & 63;
    const int lrow = lane & 15;
    const int quad = lane >> 4;
    const int m = wave * 16 + lrow;

    f32x4 acc0 = {0.f, 0.f, 0.f, 0.f};
    f32x4 acc1 = {0.f, 0.f, 0.f, 0.f};
    f32x4 acc2 = {0.f, 0.f, 0.f, 0.f};
    f32x4 acc3 = {0.f, 0.f, 0.f, 0.f};

#pragma unroll
    for (int kt = 0; kt < K / 32; kt++) {
        int k0 = kt * 32 + quad * 8;
        bf16x8 a = *(const bf16x8*)&As[m * KP + k0];
        bf16x8 b0 = *(const bf16x8*)&Wt[(0 * 16 + lrow) * KP + k0];
        bf16x8 b1 = *(const bf16x8*)&Wt[(1 * 16 + lrow) * KP + k0];
        bf16x8 b2 = *(const bf16x8*)&Wt[(2 * 16 + lrow) * KP + k0];
        bf16x8 b3 = *(const bf16x8*)&Wt[(3 * 16 + lrow) * KP + k0];
        acc0 = __builtin_amdgcn_mfma_f32_16x16x32_bf16(a, b0, acc0, 0, 0, 0);
        acc1 = __builtin_amdgcn_mfma_f32_16x16x32_bf16(a, b1, acc1, 0, 0, 0);
        acc2 = __builtin_amdgcn_mfma_f32_16x16x32_bf16(a, b2, acc2, 0, 0, 0);
        acc3 = __builtin_amdgcn_mfma_f32_16x16x32_bf16(a, b3, acc3, 0, 0, 0);
    }

    f32x4 accs[4] = {acc0, acc1, acc2, acc3};
#pragma unroll
    for (int c = 0; c < 4; c++) {
#pragma unroll
        for (int r = 0; r < 4; r++) {
            int row = row0 + wave * 16 + quad * 4 + r;
            if (row < N_NODES) H[(size_t)row * 64 + c * 16 + lrow] = f2bf(accs[c][r]);
        }
    }
}

// ===========================================================================
// scatterA2: bucket-sort edges, 4096 edges/block, packed int2 {dst,src}.
// ===========================================================================
__global__ __launch_bounds__(256)
void scatterA2_kernel(const int* __restrict__ src, const int* __restrict__ dst,
                      const int* __restrict__ posA, int2* __restrict__ edgeA) {
    __shared__ int off[NB];
    int tid = threadIdx.x, blk = blockIdx.x;
    for (int b = tid; b < NB; b += 256) off[b] = posA[b * EB + blk * 4];
    __syncthreads();
    int base = blk * 4096 + tid;
#pragma unroll
    for (int j = 0; j < 16; j++) {
        int t = base + j * 256;
        if (t < N_EDGES) {
            int d = dst[t];
            int r = atomicAdd(&off[d >> 9], 1);
            edgeA[r] = make_int2(d, src[t]);
        }
    }
}

// ===========================================================================
// passB: one block per bucket. Local hist -> dinv, local scan -> noffs,
// LDS scatter -> node-major srcs2.
// ===========================================================================
__global__ __launch_bounds__(256)
void passB_kernel(const int* __restrict__ posA, const int2* __restrict__ edgeA,
                  int* __restrict__ noffs, float* __restrict__ dinv,
                  int* __restrict__ srcs2) {
    __shared__ int hist[512];
    __shared__ int off[512];
    __shared__ int ps[256];
    __shared__ int srcs_l[BCAP];

    int tid = threadIdx.x, b = blockIdx.x;
    int e0 = posA[b * EB];
    int e1 = posA[(b + 1) * EB];
    int n0 = b << 9;
    int nn = min(512, N_NODES - n0);
    int len = e1 - e0;

    hist[tid] = 0; hist[tid + 256] = 0;
    __syncthreads();
    for (int i = e0 + tid; i < e1; i += 256) atomicAdd(&hist[edgeA[i].x - n0], 1);
    __syncthreads();

    for (int n = tid; n < nn; n += 256) dinv[n0 + n] = rsqrtf((float)hist[n] + 1.0f);

    int a0 = hist[2 * tid], a1 = hist[2 * tid + 1];
    ps[tid] = a0 + a1;
    __syncthreads();
    for (int d = 1; d < 256; d <<= 1) {
        int v = (tid >= d) ? ps[tid - d] : 0;
        __syncthreads();
        ps[tid] += v;
        __syncthreads();
    }
    int pre = ps[tid] - (a0 + a1);
    off[2 * tid] = pre;
    off[2 * tid + 1] = pre + a0;
    __syncthreads();

    for (int n = tid; n < nn; n += 256) noffs[n0 + n] = e0 + off[n];
    if (b == NB - 1 && tid == 0) noffs[N_NODES] = N_EDGES;
    __syncthreads();

    if (len <= BCAP) {
        for (int i = e0 + tid; i < e1; i += 256) {
            int2 e = edgeA[i];
            int r = atomicAdd(&off[e.x - n0], 1);
            srcs_l[r] = e.y;
        }
        __syncthreads();
        for (int i = tid; i < len; i += 256) srcs2[e0 + i] = srcs_l[i];
    } else {
        for (int i = e0 + tid; i < e1; i += 256) {
            int2 e = edgeA[i];
            int r = atomicAdd(&off[e.x - n0], 1);
            srcs2[e0 + r] = e.y;
        }
    }
}

// ===========================================================================
// MFMA GEMM (layer 2): bf16 in, fp8-e4m3 out (HW cvt), K=64.
// ===========================================================================
template <int K>
__global__ __launch_bounds__(256)
void gemm_mfma_fp8out_kernel(const unsigned short* __restrict__ X, const float* __restrict__ W,
                             unsigned char* __restrict__ H8, int n_rows) {
    constexpr int KP = K + 8;
    __shared__ unsigned short As[64 * KP];
    __shared__ unsigned short Wt[64 * KP];

    const int tid  = threadIdx.x;
    const int row0 = blockIdx.x * 64;

    for (int i = tid; i < K * 64; i += 256) {
        int k = i >> 6;
        int n = i & 63;
        Wt[n * KP + k] = f2bf(W[i]);
    }
    constexpr int KQ = K / 8;
    for (int i = tid; i < 64 * KQ; i += 256) {
        int r = i / KQ, k8 = i % KQ;
        int row = row0 + r;
        int4 v = make_int4(0, 0, 0, 0);
        if (row < n_rows) v = ((const int4*)(X + (size_t)row * K))[k8];
        *(int4*)&As[r * KP + k8 * 8] = v;
    }
    __syncthreads();

    const int wave = tid >> 6;
    const int lane = tid & 63;
    const int lrow = lane & 15;
    const int quad = lane >> 4;
    const int m = wave * 16 + lrow;

    f32x4 acc0 = {0.f, 0.f, 0.f, 0.f};
    f32x4 acc1 = {0.f, 0.f, 0.f, 0.f};
    f32x4 acc2 = {0.f, 0.f, 0.f, 0.f};
    f32x4 acc3 = {0.f, 0.f, 0.f, 0.f};

#pragma unroll
    for (int kt = 0; kt < K / 32; kt++) {
        int k0 = kt * 32 + quad * 8;
        bf16x8 a = *(const bf16x8*)&As[m * KP + k0];
        bf16x8 b0 = *(const bf16x8*)&Wt[(0 * 16 + lrow) * KP + k0];
        bf16x8 b1 = *(const bf16x8*)&Wt[(1 * 16 + lrow) * KP + k0];
        bf16x8 b2 = *(const bf16x8*)&Wt[(2 * 16 + lrow) * KP + k0];
        bf16x8 b3 = *(const bf16x8*)&Wt[(3 * 16 + lrow) * KP + k0];
        acc0 = __builtin_amdgcn_mfma_f32_16x16x32_bf16(a, b0, acc0, 0, 0, 0);
        acc1 = __builtin_amdgcn_mfma_f32_16x16x32_bf16(a, b1, acc1, 0, 0, 0);
        acc2 = __builtin_amdgcn_mfma_f32_16x16x32_bf16(a, b2, acc2, 0, 0, 0);
        acc3 = __builtin_amdgcn_mfma_f32_16x16x32_bf16(a, b3, acc3, 0, 0, 0);
    }

    f32x4 accs[4] = {acc0, acc1, acc2, acc3};
#pragma unroll
    for (int c = 0; c < 4; c++) {
#pragma unroll
        for (int r = 0; r < 4; r++) {
            int row = row0 + wave * 16 + quad * 4 + r;
            if (row < n_rows) {
                int p = __builtin_amdgcn_cvt_pk_fp8_f32(accs[c][r], accs[c][r], 0, false);
                H8[(size_t)row * 64 + c * 16 + lrow] = (unsigned char)(p & 0xFF);
            }
        }
    }
}

// ===========================================================================
// Gather A (layer 1): bf16 table, 8 lanes/node, x4 unroll -> bf16 out.
// ===========================================================================
__device__ inline void upk_fma(int4 u, float c, float* acc) {
    unsigned int a = (unsigned int)u.x, b = (unsigned int)u.y;
    unsigned int d = (unsigned int)u.z, e = (unsigned int)u.w;
    acc[0] += __uint_as_float(a << 16) * c;
    acc[1] += __uint_as_float(a & 0xFFFF0000u) * c;
    acc[2] += __uint_as_float(b << 16) * c;
    acc[3] += __uint_as_float(b & 0xFFFF0000u) * c;
    acc[4] += __uint_as_float(d << 16) * c;
    acc[5] += __uint_as_float(d & 0xFFFF0000u) * c;
    acc[6] += __uint_as_float(e << 16) * c;
    acc[7] += __uint_as_float(e & 0xFFFF0000u) * c;
}

__global__ __launch_bounds__(256)
void gather_flat_kernel(const int* __restrict__ offs, const int* __restrict__ srcs,
                        const float* __restrict__ dinv, const unsigned short* __restrict__ h,
                        const float* __restrict__ b, unsigned short* __restrict__ out,
                        int n_nodes) {
    int t = blockIdx.x * 256 + threadIdx.x;
    int node = t >> 3;
    if (node >= n_nodes) return;
    int cg = (t & 7) * 8;

    float dn = dinv[node];
    float acc[8];
    {
        int4 u = *(const int4*)(h + (size_t)node * 64 + cg);
        float c2 = dn * dn;
        for (int j = 0; j < 8; j++) acc[j] = 0.f;
        upk_fma(u, c2, acc);
    }

    int i  = offs[node];
    int i1 = offs[node + 1];
    for (; i + 4 <= i1; i += 4) {
        int s0 = srcs[i];
        int s1 = srcs[i + 1];
        int s2 = srcs[i + 2];
        int s3 = srcs[i + 3];
        float c0 = dinv[s0] * dn;
        float c1 = dinv[s1] * dn;
        float c2 = dinv[s2] * dn;
        float c3 = dinv[s3] * dn;
        int4 u0 = *(const int4*)(h + (size_t)s0 * 64 + cg);
        int4 u1 = *(const int4*)(h + (size_t)s1 * 64 + cg);
        int4 u2 = *(const int4*)(h + (size_t)s2 * 64 + cg);
        int4 u3 = *(const int4*)(h + (size_t)s3 * 64 + cg);
        upk_fma(u0, c0, acc);
        upk_fma(u1, c1, acc);
        upk_fma(u2, c2, acc);
        upk_fma(u3, c3, acc);
    }
    for (; i < i1; i++) {
        int s0 = srcs[i];
        float c0 = dinv[s0] * dn;
        int4 u0 = *(const int4*)(h + (size_t)s0 * 64 + cg);
        upk_fma(u0, c0, acc);
    }

    float4 b0 = *(const float4*)(b + cg);
    float4 b1 = *(const float4*)(b + cg + 4);
    unsigned short* o = out + (size_t)node * 64 + cg;
    ushort4 p0 = make_ushort4(f2bf(fmaxf(acc[0] + b0.x, 0.f)), f2bf(fmaxf(acc[1] + b0.y, 0.f)),
                              f2bf(fmaxf(acc[2] + b0.z, 0.f)), f2bf(fmaxf(acc[3] + b0.w, 0.f)));
    ushort4 p1 = make_ushort4(f2bf(fmaxf(acc[4] + b1.x, 0.f)), f2bf(fmaxf(acc[5] + b1.y, 0.f)),
                              f2bf(fmaxf(acc[6] + b1.z, 0.f)), f2bf(fmaxf(acc[7] + b1.w, 0.f)));
    *(ushort4*)(o)     = p0;
    *(ushort4*)(o + 4) = p1;
}

// ===========================================================================
// Gather B + POOL fused (layer 2): fp8 table, 8 lanes/node. Pool reduction:
// FAST path (block entirely in one graph, ~84% of blocks): shuffle butterfly
// over the 8 nodes per wave + plain LDS stores + 64 non-returning global
// atomics per block. SLOW path (boundary blocks): LDS-atomic slots.
// ===========================================================================
__device__ inline void upk8_fma(int2 u, float c, float* acc) {
    f32x2 p0 = __builtin_amdgcn_cvt_pk_f32_fp8(u.x, false);
    f32x2 p1 = __builtin_amdgcn_cvt_pk_f32_fp8(u.x, true);
    f32x2 p2 = __builtin_amdgcn_cvt_pk_f32_fp8(u.y, false);
    f32x2 p3 = __builtin_amdgcn_cvt_pk_f32_fp8(u.y, true);
    acc[0] += p0.x * c; acc[1] += p0.y * c;
    acc[2] += p1.x * c; acc[3] += p1.y * c;
    acc[4] += p2.x * c; acc[5] += p2.y * c;
    acc[6] += p3.x * c; acc[7] += p3.y * c;
}

__global__ __launch_bounds__(256)
void gather_fp8_pool_kernel(const int* __restrict__ offs, const int* __restrict__ srcs,
                            const float* __restrict__ dinv, const unsigned char* __restrict__ h8,
                            const float* __restrict__ b, const int* __restrict__ batch,
                            float* __restrict__ pooled, float* __restrict__ cnt,
                            int n_nodes) {
    __shared__ float pacc[PSLOTS][64];
    __shared__ float lcnt[PSLOTS];
    __shared__ int sg[2];

    int tid = threadIdx.x;
    int node0 = blockIdx.x * 32;
    int lastn = min(node0 + 31, n_nodes - 1);
    for (int i = tid; i < PSLOTS * 64; i += 256) ((float*)pacc)[i] = 0.f;
    if (tid < PSLOTS) lcnt[tid] = 0.f;
    if (tid == 0) { sg[0] = batch[min(node0, n_nodes - 1)]; sg[1] = batch[lastn]; }
    __syncthreads();
    int g0 = sg[0];
    bool single = (sg[0] == sg[1]);   // block-uniform

    int node = node0 + (tid >> 3);
    int cg = (tid & 7) * 8;

    float r[8];
#pragma unroll
    for (int j = 0; j < 8; j++) r[j] = 0.f;

    if (node < n_nodes) {
        float dn = dinv[node];
        float acc[8];
        {
            int2 u = *(const int2*)(h8 + (size_t)node * 64 + cg);
            float c2 = dn * dn;
            for (int j = 0; j < 8; j++) acc[j] = 0.f;
            upk8_fma(u, c2, acc);
        }

        int i  = offs[node];
        int i1 = offs[node + 1];
        for (; i + 4 <= i1; i += 4) {
            int s0 = srcs[i];
            int s1 = srcs[i + 1];
            int s2 = srcs[i + 2];
            int s3 = srcs[i + 3];
            float c0 = dinv[s0] * dn;
            float c1 = dinv[s1] * dn;
            float c2 = dinv[s2] * dn;
            float c3 = dinv[s3] * dn;
            int2 u0 = *(const int2*)(h8 + (size_t)s0 * 64 + cg);
            int2 u1 = *(const int2*)(h8 + (size_t)s1 * 64 + cg);
            int2 u2 = *(const int2*)(h8 + (size_t)s2 * 64 + cg);
            int2 u3 = *(const int2*)(h8 + (size_t)s3 * 64 + cg);
            upk8_fma(u0, c0, acc);
            upk8_fma(u1, c1, acc);
            upk8_fma(u2, c2, acc);
            upk8_fma(u3, c3, acc);
        }
        for (; i < i1; i++) {
            int s0 = srcs[i];
            float c0 = dinv[s0] * dn;
            int2 u0 = *(const int2*)(h8 + (size_t)s0 * 64 + cg);
            upk8_fma(u0, c0, acc);
        }

        float4 b0 = *(const float4*)(b + cg);
        float4 b1 = *(const float4*)(b + cg + 4);
        r[0] = fmaxf(acc[0] + b0.x, 0.f);
        r[1] = fmaxf(acc[1] + b0.y, 0.f);
        r[2] = fmaxf(acc[2] + b0.z, 0.f);
        r[3] = fmaxf(acc[3] + b0.w, 0.f);
        r[4] = fmaxf(acc[4] + b1.x, 0.f);
        r[5] = fmaxf(acc[5] + b1.y, 0.f);
        r[6] = fmaxf(acc[6] + b1.z, 0.f);
        r[7] = fmaxf(acc[7] + b1.w, 0.f);
    }

    if (single) {
        // butterfly over lanes ^8,^16,^32: sums the 8 nodes of this wave
        // (groups of lanes with equal lane&7 = same channel group)
#pragma unroll
        for (int j = 0; j < 8; j++) {
            float v = r[j];
            v += __shfl_xor(v, 8);
            v += __shfl_xor(v, 16);
            v += __shfl_xor(v, 32);
            r[j] = v;
        }
        int wave = tid >> 6;
        int lane = tid & 63;
        if (lane < 8) {
#pragma unroll
            for (int j = 0; j < 8; j++) pacc[wave][lane * 8 + j] = r[j];
        }
        __syncthreads();
        if (tid < 64) {
            float s = pacc[0][tid] + pacc[1][tid] + pacc[2][tid] + pacc[3][tid];
            if (s != 0.f) unsafeAtomicAdd(&pooled[(size_t)g0 * 64 + tid], s);
        }
        if (tid == 0) {
            int valid = min(32, n_nodes - node0);
            unsafeAtomicAdd(&cnt[g0], (float)valid);
        }
    } else {
        if (node < n_nodes) {
            int g = batch[node];
            int slot = g - g0;          // batch sorted -> slot >= 0
            if (slot < PSLOTS) {
#pragma unroll
                for (int j = 0; j < 8; j++) atomicAdd(&pacc[slot][cg + j], r[j]);
                if ((tid & 7) == 0) atomicAdd(&lcnt[slot], 1.f);
            } else {
#pragma unroll
                for (int j = 0; j < 8; j++) unsafeAtomicAdd(&pooled[(size_t)g * 64 + cg + j], r[j]);
                if ((tid & 7) == 0) unsafeAtomicAdd(&cnt[g], 1.f);
            }
        }
        __syncthreads();
        for (int i = tid; i < PSLOTS * 64; i += 256) {
            float v = ((float*)pacc)[i];
            if (v != 0.f) unsafeAtomicAdd(&pooled[(size_t)(g0 + (i >> 6)) * 64 + (i & 63)], v);
        }
        if (tid < PSLOTS && lcnt[tid] != 0.f) unsafeAtomicAdd(&cnt[g0 + tid], lcnt[tid]);
    }
}

// ===========================================================================
// Head: pooled mean -> logits -> log_softmax.
// ===========================================================================
__global__ __launch_bounds__(256)
void head_kernel(const float* __restrict__ pooled, const float* __restrict__ cnt,
                 const float* __restrict__ Wfc, const float* __restrict__ bfc,
                 float* __restrict__ out) {
    __shared__ float Ws[HIDDEN * N_CLASSES];
    __shared__ float bs[N_CLASSES];
    int tid = threadIdx.x;
    for (int i = tid; i < HIDDEN * N_CLASSES; i += 256) Ws[i] = Wfc[i];
    if (tid < N_CLASSES) bs[tid] = bfc[tid];
    __syncthreads();

    int g = blockIdx.x * 256 + tid;
    if (g >= N_GRAPHS) return;

    float inv = 1.f / fmaxf(cnt[g], 1.f);
    float p[HIDDEN];
#pragma unroll
    for (int k = 0; k < HIDDEN; k++) p[k] = pooled[(size_t)g * 64 + k] * inv;

    float lg[N_CLASSES];
    float m = -1e30f;
#pragma unroll
    for (int j = 0; j < N_CLASSES; j++) {
        float a = bs[j];
#pragma unroll
        for (int k = 0; k < HIDDEN; k++) a += p[k] * Ws[k * N_CLASSES + j];
        lg[j] = a;
        m = fmaxf(m, a);
    }
    float s = 0.f;
#pragma unroll
    for (int j = 0; j < N_CLASSES; j++) s += __expf(lg[j] - m);
    float lse = m + __logf(s);
#pragma unroll
    for (int j = 0; j < N_CLASSES; j++) out[(size_t)g * N_CLASSES + j] = lg[j] - lse;
}

// ===========================================================================
// Launch
// ===========================================================================
extern "C" void kernel_launch(void* const* d_in, const int* in_sizes, int n_in,
                              void* d_out, int out_size, void* d_ws, size_t ws_size,
                              hipStream_t stream) {
    const float* x   = (const float*)d_in[0];
    const int*   ei  = (const int*)d_in[1];
    const int*   bat = (const int*)d_in[2];
    const float* W1  = (const float*)d_in[3];
    const float* b1  = (const float*)d_in[4];
    const float* W2  = (const float*)d_in[5];
    const float* b2  = (const float*)d_in[6];
    const float* Wfc = (const float*)d_in[7];
    const float* bfc = (const float*)d_in[8];
    float* out = (float*)d_out;

    const int* src = ei;
    const int* dst = ei + N_EDGES;

    char* ws = (char*)d_ws;

    // Layout, total ~53.8 MB:
    const size_t OFF_H     = 0;          // h1 bf16 12.8 MB; later h2 fp8 6.4 MB
    const size_t OFF_SRCS2 = 12800000;   // node-major srcs 6.4 MB
    const size_t OFF_NOFFS = 19200000;   // 400,016
    const size_t OFF_DINV  = 19600016;   // 400,000
    const size_t OFF_BUFB  = 25600000;   // h1r bf16 12.8 MB
    const size_t OFF_EDGEA = 38400000;   // 12.8 MB int2 {dst,src} (build only)
    const size_t OFF_HA    = 51200000;   // 1,225,392
    const size_t OFF_POSA  = 52425392;   // 1,225,396 (NBE+1 ints)
    const size_t OFF_BSUM  = 53650800;   // 1,024
    const size_t OFF_POOL  = 53651824;   // 131,072
    const size_t OFF_CNT   = 53782896;   // 2,048

    unsigned short* hbuf  = (unsigned short*)(ws + OFF_H);
    unsigned char*  hbuf8 = (unsigned char*) (ws + OFF_H);
    int*   srcs2  = (int*)  (ws + OFF_SRCS2);
    int*   noffs  = (int*)  (ws + OFF_NOFFS);
    float* dinv   = (float*)(ws + OFF_DINV);
    unsigned short* bufB16 = (unsigned short*)(ws + OFF_BUFB);
    int2*  edgeA  = (int2*) (ws + OFF_EDGEA);
    int*   HA     = (int*)  (ws + OFF_HA);
    int*   posA   = (int*)  (ws + OFF_POSA);
    int*   bsum   = (int*)  (ws + OFF_BSUM);
    float* pooled = (float*)(ws + OFF_POOL);
    float* cnt    = (float*)(ws + OFF_CNT);

    const int SCAN_BLOCKS = (NBE + 4095) / 4096;          // 75
    const int GATHER_BLOCKS = (N_NODES * 8 + 255) / 256;  // 3125
    const int GEMM_BLOCKS = (N_NODES + 63) / 64;          // 1563

    hipMemsetAsync(pooled, 0, (size_t)(N_GRAPHS * 64 + N_GRAPHS) * sizeof(float), stream);

    // 1. gemm1 (even blocks) + bucket histogram via LDS (odd blocks)
    fused1_kernel<<<2 * GEMM_BLOCKS, 256, 0, stream>>>(x, W1, hbuf, dst, HA);
    // 2. scan the (bucket, block) count matrix -> exclusive slots
    scan1_kernel<<<SCAN_BLOCKS, 256, 0, stream>>>(HA, bsum, NBE);
    scan2_kernel<<<1, 256, 0, stream>>>(bsum, posA, SCAN_BLOCKS, NBE);
    scan3_kernel<<<SCAN_BLOCKS, 256, 0, stream>>>(HA, bsum, posA, NBE);
    // 3. bucket-sort edges: 4096-edge blocks, packed int2, no global atomics
    scatterA2_kernel<<<EB4, 256, 0, stream>>>(src, dst, posA, edgeA);
    // 4. per-bucket CSR build: degrees->dinv, noffs, node-major srcs2
    passB_kernel<<<NB, 256, 0, stream>>>(posA, edgeA, noffs, dinv, srcs2);

    // 5. gather1 (bf16 table): h1 -> h1r bf16
    gather_flat_kernel<<<GATHER_BLOCKS, 256, 0, stream>>>(noffs, srcs2, dinv, hbuf, b1, bufB16, N_NODES);
    // 6. gemm2: h1r bf16 -> h2 fp8
    gemm_mfma_fp8out_kernel<HIDDEN><<<GEMM_BLOCKS, 256, 0, stream>>>(bufB16, W2, hbuf8, N_NODES);
    // 7. gather2 + pool fused: shuffle-reduced pooling (no LDS atomics on fast path)
    gather_fp8_pool_kernel<<<GATHER_BLOCKS, 256, 0, stream>>>(
        noffs, srcs2, dinv, hbuf8, b2, bat, pooled, cnt, N_NODES);

    // 8. head
    head_kernel<<<(N_GRAPHS + 255) / 256, 256, 0, stream>>>(pooled, cnt, Wfc, bfc, out);
}